// Round 1
// baseline (626.437 us; speedup 1.0000x reference)
//
#include <hip/hip_runtime.h>
#include <cstdint>

// DynamicExpert: act = topk60(sigmoid(act @ synapse.T)), 2 steps.
// B=8, DIM=8192, fp32. Memory-bound on streaming W (268 MB) per step.
// R2: gemv 8 rows/block (A:W VMEM 1:1, halved A traffic) + explicit
//     next-window double-buffer prefetch; topk via 3-level radix histogram
//     (~10 barriers) instead of 30-iteration binary search (~60 barriers).

#define DIM 8192
#define BATCH 8

__device__ __forceinline__ float sigmoidf_(float x) {
    return 1.0f / (1.0f + __expf(-x));
}

// Y[b][i] = sigmoid( sum_j A[b][j] * W[i][j] ), A:[8][8192], W:[8192][8192].
// Block -> rows 8*bid..8*bid+7. Wave w covers j in [w*2048, (w+1)*2048) in
// 8 windows of 256 j; per window a lane holds 8 A float4 + 8 W float4 and
// prefetches the next window's 16 float4 before the 256-FMA burst.
// Per-lane accumulation order identical to R1 -> bit-identical sums.
__global__ __launch_bounds__(256) void gemv8_sigmoid(
    const float* __restrict__ A,
    const float* __restrict__ W,
    float* __restrict__ Y)
{
    const int lane = threadIdx.x & 63;
    const int wid  = threadIdx.x >> 6;
    const int row0 = blockIdx.x * 8;
    const int jbeg = wid * (DIM / 4) + lane * 4;

    const float* arow = A + jbeg;
    const float* wrow[8];
#pragma unroll
    for (int r = 0; r < 8; ++r)
        wrow[r] = W + (size_t)(row0 + r) * DIM + jbeg;

    float4 a0[8], w0[8], a1[8], w1[8];
#pragma unroll
    for (int b = 0; b < 8; ++b) a0[b] = *(const float4*)(arow + (size_t)b * DIM);
#pragma unroll
    for (int r = 0; r < 8; ++r) w0[r] = *(const float4*)(wrow[r]);

    float acc[8][8];
#pragma unroll
    for (int r = 0; r < 8; ++r)
#pragma unroll
        for (int b = 0; b < 8; ++b) acc[r][b] = 0.0f;

#pragma unroll
    for (int win = 0; win < 8; ++win) {
        const int off = (win + 1) * 256;
        if (win < 7) {
#pragma unroll
            for (int b = 0; b < 8; ++b)
                a1[b] = *(const float4*)(arow + (size_t)b * DIM + off);
#pragma unroll
            for (int r = 0; r < 8; ++r)
                w1[r] = *(const float4*)(wrow[r] + off);
        }
#pragma unroll
        for (int r = 0; r < 8; ++r) {
#pragma unroll
            for (int b = 0; b < 8; ++b) {
                acc[r][b] += w0[r].x * a0[b].x;
                acc[r][b] += w0[r].y * a0[b].y;
                acc[r][b] += w0[r].z * a0[b].z;
                acc[r][b] += w0[r].w * a0[b].w;
            }
        }
#pragma unroll
        for (int b = 0; b < 8; ++b) a0[b] = a1[b];
#pragma unroll
        for (int r = 0; r < 8; ++r) w0[r] = w1[r];
    }

    // wave-reduce the 64 sums over 64 lanes -> lane 0 (same tree as R1)
    __shared__ float part[4][8][8];   // [wave][r][b]
#pragma unroll
    for (int r = 0; r < 8; ++r) {
#pragma unroll
        for (int b = 0; b < 8; ++b) {
            float v = acc[r][b];
#pragma unroll
            for (int o = 32; o > 0; o >>= 1)
                v += __shfl_down(v, o, 64);
            if (lane == 0) part[wid][r][b] = v;
        }
    }
    __syncthreads();

    if (threadIdx.x < 64) {
        const int r = threadIdx.x >> 3;
        const int b = threadIdx.x & 7;
        const float s = part[0][r][b] + part[1][r][b]
                      + part[2][r][b] + part[3][r][b];
        Y[(size_t)b * DIM + row0 + r] = sigmoidf_(s);
    }
}

// ---- top-k via 3-level radix histogram on float bits -------------------
// Values are sigmoid outputs in (0, 1]; positive floats -> uint bit order
// == float order. Level 1: bits>>17 (8192 buckets, 32 KB LDS); level 2:
// (bits>>8)&0x1FF (512); level 3: bits&0xFF (256). Each level: LDS-atomic
// histogram, then wave 0 does a suffix scan from the top bucket to find
// the bucket containing the k-th largest and the count strictly above it.

// Suffix-scan over nb (<=512, multiple of 64) buckets, wave 0 only.
__device__ __forceinline__ void scan_small(const int* hist, int nb, int k_need,
                                           int lane, int* s_cut, int* s_gt)
{
    int running = 0;
    for (int cb = nb - 64; cb >= 0; cb -= 64) {
        const int b = cb + 63 - lane;          // lane 0 = highest bucket
        const int val = hist[b];
        int c = val;
#pragma unroll
        for (int o = 1; o < 64; o <<= 1) {
            const int u = __shfl_up(c, o, 64);
            if (lane >= o) c += u;
        }
        const unsigned long long m = __ballot(running + c >= k_need);
        if (m) {
            const int f = (int)__ffsll(m) - 1;
            const int cf = __shfl(c, f, 64);
            const int vf = __shfl(val, f, 64);
            if (lane == 0) { *s_cut = cb + 63 - f; *s_gt = running + cf - vf; }
            return;
        }
        running += __shfl(c, 63, 64);
    }
    if (lane == 0) { *s_cut = 0; *s_gt = 0; }  // unreachable for valid k
}

// Level-1 scan over 8192 buckets using 256 precomputed coarse sums (32 each).
__device__ __forceinline__ void scan_l1(const int* hist, const int* coarse,
                                        int k_need, int lane,
                                        int* s_cut, int* s_gt)
{
    int running = 0, seg = -1, segGT = 0;
    for (int cb = 192; cb >= 0 && seg < 0; cb -= 64) {
        const int b = cb + 63 - lane;
        const int val = coarse[b];
        int c = val;
#pragma unroll
        for (int o = 1; o < 64; o <<= 1) {
            const int u = __shfl_up(c, o, 64);
            if (lane >= o) c += u;
        }
        const unsigned long long m = __ballot(running + c >= k_need);
        if (m) {
            const int f = (int)__ffsll(m) - 1;
            seg = cb + 63 - f;
            segGT = running + __shfl(c, f, 64) - __shfl(val, f, 64);
        } else {
            running += __shfl(c, 63, 64);
        }
    }
    if (seg < 0) seg = 0;                      // defensive; valid k never hits
    // fine scan of the 32 buckets inside the chosen segment
    const int b = seg * 32 + 31 - lane;
    const int val = (lane < 32) ? hist[b] : 0;
    int c = val;
#pragma unroll
    for (int o = 1; o < 64; o <<= 1) {
        const int u = __shfl_up(c, o, 64);
        if (lane >= o) c += u;
    }
    const unsigned long long m = __ballot(segGT + c >= k_need);
    const int f = (int)__ffsll(m) - 1;         // crossing is within lanes 0..31
    const int cf = __shfl(c, f, 64);
    const int vf = __shfl(val, f, 64);
    if (lane == 0) { *s_cut = seg * 32 + 31 - f; *s_gt = segGT + cf - vf; }
}

// Per row (block): keep top-k values, zero the rest. In-place safe: all
// loads complete before the first __syncthreads(). Tie semantics match R1
// (need_eq ties claimed via shared atomic).
__global__ __launch_bounds__(256) void topk_sparsify(
    const float* __restrict__ Yin,
    float* __restrict__ Yout,
    const int* __restrict__ kptr)
{
    const int row  = blockIdx.x;
    const int tid  = threadIdx.x;
    const int lane = tid & 63;
    const int wid  = tid >> 6;
    int k = kptr ? *kptr : 60;
    if (k > DIM) k = DIM;

    uint32_t v[32];
    const float* src = Yin + (size_t)row * DIM;
#pragma unroll
    for (int i = 0; i < 32; ++i)
        v[i] = __float_as_uint(src[tid + i * 256]);

    float* dst = Yout + (size_t)row * DIM;
    if (k <= 0) {
#pragma unroll
        for (int i = 0; i < 32; ++i) dst[tid + i * 256] = 0.0f;
        return;
    }

    __shared__ int hist[8192];     // 32 KB
    __shared__ int coarse[256];
    __shared__ int s_cut, s_gt, s_ctr;

    // ---- level 1: bits >> 17 (max idx 0x3F800000>>17 = 8129 < 8192) ----
    for (int i = tid; i < 8192; i += 256) hist[i] = 0;
    __syncthreads();
#pragma unroll
    for (int i = 0; i < 32; ++i) atomicAdd(&hist[v[i] >> 17], 1);
    __syncthreads();
    {
        int s = 0;
        const int base = tid * 32;
        for (int i = 0; i < 32; ++i) s += hist[base + i];
        coarse[tid] = s;
    }
    __syncthreads();
    if (wid == 0) scan_l1(hist, coarse, k, lane, &s_cut, &s_gt);
    __syncthreads();
    const uint32_t cut1 = (uint32_t)s_cut;
    const int gt1 = s_gt;

    // ---- level 2: (bits >> 8) & 0x1FF among level-1 bucket matches ----
    for (int i = tid; i < 512; i += 256) hist[i] = 0;
    __syncthreads();
#pragma unroll
    for (int i = 0; i < 32; ++i)
        if ((v[i] >> 17) == cut1) atomicAdd(&hist[(v[i] >> 8) & 0x1FF], 1);
    __syncthreads();
    if (wid == 0) scan_small(hist, 512, k - gt1, lane, &s_cut, &s_gt);
    __syncthreads();
    const uint32_t cut2 = (uint32_t)s_cut;
    const int gt2 = s_gt;

    // ---- level 3: bits & 0xFF among level-2 matches ----
    const uint32_t pref = (cut1 << 9) | cut2;   // == (v >> 8) for matches
    for (int i = tid; i < 256; i += 256) hist[i] = 0;
    if (tid == 0) s_ctr = 0;
    __syncthreads();
#pragma unroll
    for (int i = 0; i < 32; ++i)
        if ((v[i] >> 8) == pref) atomicAdd(&hist[v[i] & 0xFF], 1);
    __syncthreads();
    if (wid == 0) scan_small(hist, 256, k - gt1 - gt2, lane, &s_cut, &s_gt);
    __syncthreads();
    const uint32_t cut3 = (uint32_t)s_cut;
    const int gt3 = s_gt;

    const uint32_t cutoff  = (pref << 8) | cut3;   // k-th largest value's bits
    const int      need_eq = k - (gt1 + gt2 + gt3);

#pragma unroll
    for (int i = 0; i < 32; ++i) {
        const uint32_t b = v[i];
        float val = 0.0f;
        if (b > cutoff) {
            val = __uint_as_float(b);
        } else if (b == cutoff) {
            const int pos = atomicAdd(&s_ctr, 1);
            if (pos < need_eq) val = __uint_as_float(b);
        }
        dst[tid + i * 256] = val;
    }
}

extern "C" void kernel_launch(void* const* d_in, const int* in_sizes, int n_in,
                              void* d_out, int out_size, void* d_ws, size_t ws_size,
                              hipStream_t stream) {
    const float* sdr = (const float*)d_in[0];
    const float* syn = (const float*)d_in[1];
    const int* kptr  = (n_in > 3) ? (const int*)d_in[3] : nullptr;
    float* out = (float*)d_out;
    float* tmp = (float*)d_ws;            // scratch for step-2 pre-sparsify

    // step 1: y = sigmoid(sdr @ W^T) -> d_out (scratch), sparsify in place
    gemv8_sigmoid<<<1024, 256, 0, stream>>>(sdr, syn, out);
    topk_sparsify<<<8, 256, 0, stream>>>(out, out, kptr);
    // step 2: y = sigmoid(act1 @ W^T) -> ws, sparsify -> d_out
    gemv8_sigmoid<<<1024, 256, 0, stream>>>(out, syn, tmp);
    topk_sparsify<<<8, 256, 0, stream>>>(tmp, out, kptr);
}

// Round 2
// 572.101 us; speedup vs baseline: 1.0950x; 1.0950x over previous
//
#include <hip/hip_runtime.h>
#include <cstdint>

// DynamicExpert: act = topk60(sigmoid(act @ synapse.T)), 2 steps.
// B=8, DIM=8192, fp32. Memory-bound on streaming W (268 MB) per step.
// R3: revert gemv to R1 geometry (4 rows/block, 2048 blocks, ~16 waves/CU)
//     — R2's 8-row full double-buffer hit the 256-VGPR cap (occupancy 11%,
//     190 us). Add a one-window W-prefetch (streamed operand only, +16 VGPR)
//     so the HBM stream stays in flight across the FMA burst. Per-lane
//     j-order identical to R1 -> bit-identical sums. Radix topk kept (R2).

#define DIM 8192
#define BATCH 8

__device__ __forceinline__ float sigmoidf_(float x) {
    return 1.0f / (1.0f + __expf(-x));
}

// Y[b][i] = sigmoid( sum_j A[b][j] * W[i][j] ), A:[8][8192], W:[8192][8192].
// Block b -> rows 4b..4b+3. Wave w covers j in [w*2048, (w+1)*2048) in 8
// windows of 256 j. Per window: issue 8 A float4 (L2-hot), rename the
// prefetched W window, issue next W window (4 float4, HBM stream), then
// 128 FMAs. vmcnt order: A issued before W-next, so waiting for A does not
// drain the W prefetch.
__global__ __launch_bounds__(256) void gemv4_sigmoid(
    const float* __restrict__ A,
    const float* __restrict__ W,
    float* __restrict__ Y)
{
    const int lane = threadIdx.x & 63;
    const int wid  = threadIdx.x >> 6;
    const int row0 = blockIdx.x * 4;
    const int jbeg = wid * (DIM / 4) + lane * 4;

    const float* arow = A + jbeg;
    const float* wrow = W + (size_t)row0 * DIM + jbeg;

    float4 wn[4];
#pragma unroll
    for (int r = 0; r < 4; ++r)
        wn[r] = *(const float4*)(wrow + (size_t)r * DIM);

    float acc[4][8];
#pragma unroll
    for (int r = 0; r < 4; ++r)
#pragma unroll
        for (int b = 0; b < 8; ++b) acc[r][b] = 0.0f;

#pragma unroll
    for (int win = 0; win < 8; ++win) {
        const int off = win * 256;
        float4 a[8];
#pragma unroll
        for (int b = 0; b < 8; ++b)
            a[b] = *(const float4*)(arow + (size_t)b * DIM + off);
        float4 wc[4];
#pragma unroll
        for (int r = 0; r < 4; ++r) wc[r] = wn[r];
        if (win < 7) {
#pragma unroll
            for (int r = 0; r < 4; ++r)
                wn[r] = *(const float4*)(wrow + (size_t)r * DIM + off + 256);
        }
#pragma unroll
        for (int r = 0; r < 4; ++r) {
#pragma unroll
            for (int b = 0; b < 8; ++b) {
                acc[r][b] += wc[r].x * a[b].x;
                acc[r][b] += wc[r].y * a[b].y;
                acc[r][b] += wc[r].z * a[b].z;
                acc[r][b] += wc[r].w * a[b].w;
            }
        }
    }

    // wave-reduce each of the 32 sums over 64 lanes -> lane 0 (same as R1)
    __shared__ float part[4][4][8];   // [wave][r][b]
#pragma unroll
    for (int r = 0; r < 4; ++r) {
#pragma unroll
        for (int b = 0; b < 8; ++b) {
            float v = acc[r][b];
#pragma unroll
            for (int o = 32; o > 0; o >>= 1)
                v += __shfl_down(v, o, 64);
            if (lane == 0) part[wid][r][b] = v;
        }
    }
    __syncthreads();

    // combine 4 wave-partials, sigmoid, store (32 threads active)
    if (threadIdx.x < 32) {
        const int r = threadIdx.x >> 3;
        const int b = threadIdx.x & 7;
        const float s = part[0][r][b] + part[1][r][b]
                      + part[2][r][b] + part[3][r][b];
        Y[(size_t)b * DIM + row0 + r] = sigmoidf_(s);
    }
}

// ---- top-k via 3-level radix histogram on float bits -------------------
// Values are sigmoid outputs in (0, 1]; positive floats -> uint bit order
// == float order. Level 1: bits>>17 (8192 buckets, 32 KB LDS); level 2:
// (bits>>8)&0x1FF (512); level 3: bits&0xFF (256). Each level: LDS-atomic
// histogram, then wave 0 does a suffix scan from the top bucket to find
// the bucket containing the k-th largest and the count strictly above it.

// Suffix-scan over nb (<=512, multiple of 64) buckets, wave 0 only.
__device__ __forceinline__ void scan_small(const int* hist, int nb, int k_need,
                                           int lane, int* s_cut, int* s_gt)
{
    int running = 0;
    for (int cb = nb - 64; cb >= 0; cb -= 64) {
        const int b = cb + 63 - lane;          // lane 0 = highest bucket
        const int val = hist[b];
        int c = val;
#pragma unroll
        for (int o = 1; o < 64; o <<= 1) {
            const int u = __shfl_up(c, o, 64);
            if (lane >= o) c += u;
        }
        const unsigned long long m = __ballot(running + c >= k_need);
        if (m) {
            const int f = (int)__ffsll(m) - 1;
            const int cf = __shfl(c, f, 64);
            const int vf = __shfl(val, f, 64);
            if (lane == 0) { *s_cut = cb + 63 - f; *s_gt = running + cf - vf; }
            return;
        }
        running += __shfl(c, 63, 64);
    }
    if (lane == 0) { *s_cut = 0; *s_gt = 0; }  // unreachable for valid k
}

// Level-1 scan over 8192 buckets using 256 precomputed coarse sums (32 each).
__device__ __forceinline__ void scan_l1(const int* hist, const int* coarse,
                                        int k_need, int lane,
                                        int* s_cut, int* s_gt)
{
    int running = 0, seg = -1, segGT = 0;
    for (int cb = 192; cb >= 0 && seg < 0; cb -= 64) {
        const int b = cb + 63 - lane;
        const int val = coarse[b];
        int c = val;
#pragma unroll
        for (int o = 1; o < 64; o <<= 1) {
            const int u = __shfl_up(c, o, 64);
            if (lane >= o) c += u;
        }
        const unsigned long long m = __ballot(running + c >= k_need);
        if (m) {
            const int f = (int)__ffsll(m) - 1;
            seg = cb + 63 - f;
            segGT = running + __shfl(c, f, 64) - __shfl(val, f, 64);
        } else {
            running += __shfl(c, 63, 64);
        }
    }
    if (seg < 0) seg = 0;                      // defensive; valid k never hits
    // fine scan of the 32 buckets inside the chosen segment
    const int b = seg * 32 + 31 - lane;
    const int val = (lane < 32) ? hist[b] : 0;
    int c = val;
#pragma unroll
    for (int o = 1; o < 64; o <<= 1) {
        const int u = __shfl_up(c, o, 64);
        if (lane >= o) c += u;
    }
    const unsigned long long m = __ballot(segGT + c >= k_need);
    const int f = (int)__ffsll(m) - 1;         // crossing is within lanes 0..31
    const int cf = __shfl(c, f, 64);
    const int vf = __shfl(val, f, 64);
    if (lane == 0) { *s_cut = seg * 32 + 31 - f; *s_gt = segGT + cf - vf; }
}

// Per row (block): keep top-k values, zero the rest. In-place safe: all
// loads complete before the first __syncthreads(). Tie semantics match R1
// (need_eq ties claimed via shared atomic).
__global__ __launch_bounds__(256) void topk_sparsify(
    const float* __restrict__ Yin,
    float* __restrict__ Yout,
    const int* __restrict__ kptr)
{
    const int row  = blockIdx.x;
    const int tid  = threadIdx.x;
    const int lane = tid & 63;
    const int wid  = tid >> 6;
    int k = kptr ? *kptr : 60;
    if (k > DIM) k = DIM;

    uint32_t v[32];
    const float* src = Yin + (size_t)row * DIM;
#pragma unroll
    for (int i = 0; i < 32; ++i)
        v[i] = __float_as_uint(src[tid + i * 256]);

    float* dst = Yout + (size_t)row * DIM;
    if (k <= 0) {
#pragma unroll
        for (int i = 0; i < 32; ++i) dst[tid + i * 256] = 0.0f;
        return;
    }

    __shared__ int hist[8192];     // 32 KB
    __shared__ int coarse[256];
    __shared__ int s_cut, s_gt, s_ctr;

    // ---- level 1: bits >> 17 (max idx 0x3F800000>>17 = 8129 < 8192) ----
    for (int i = tid; i < 8192; i += 256) hist[i] = 0;
    __syncthreads();
#pragma unroll
    for (int i = 0; i < 32; ++i) atomicAdd(&hist[v[i] >> 17], 1);
    __syncthreads();
    {
        int s = 0;
        const int base = tid * 32;
        for (int i = 0; i < 32; ++i) s += hist[base + i];
        coarse[tid] = s;
    }
    __syncthreads();
    if (wid == 0) scan_l1(hist, coarse, k, lane, &s_cut, &s_gt);
    __syncthreads();
    const uint32_t cut1 = (uint32_t)s_cut;
    const int gt1 = s_gt;

    // ---- level 2: (bits >> 8) & 0x1FF among level-1 bucket matches ----
    for (int i = tid; i < 512; i += 256) hist[i] = 0;
    __syncthreads();
#pragma unroll
    for (int i = 0; i < 32; ++i)
        if ((v[i] >> 17) == cut1) atomicAdd(&hist[(v[i] >> 8) & 0x1FF], 1);
    __syncthreads();
    if (wid == 0) scan_small(hist, 512, k - gt1, lane, &s_cut, &s_gt);
    __syncthreads();
    const uint32_t cut2 = (uint32_t)s_cut;
    const int gt2 = s_gt;

    // ---- level 3: bits & 0xFF among level-2 matches ----
    const uint32_t pref = (cut1 << 9) | cut2;   // == (v >> 8) for matches
    for (int i = tid; i < 256; i += 256) hist[i] = 0;
    if (tid == 0) s_ctr = 0;
    __syncthreads();
#pragma unroll
    for (int i = 0; i < 32; ++i)
        if ((v[i] >> 8) == pref) atomicAdd(&hist[v[i] & 0xFF], 1);
    __syncthreads();
    if (wid == 0) scan_small(hist, 256, k - gt1 - gt2, lane, &s_cut, &s_gt);
    __syncthreads();
    const uint32_t cut3 = (uint32_t)s_cut;
    const int gt3 = s_gt;

    const uint32_t cutoff  = (pref << 8) | cut3;   // k-th largest value's bits
    const int      need_eq = k - (gt1 + gt2 + gt3);

#pragma unroll
    for (int i = 0; i < 32; ++i) {
        const uint32_t b = v[i];
        float val = 0.0f;
        if (b > cutoff) {
            val = __uint_as_float(b);
        } else if (b == cutoff) {
            const int pos = atomicAdd(&s_ctr, 1);
            if (pos < need_eq) val = __uint_as_float(b);
        }
        dst[tid + i * 256] = val;
    }
}

extern "C" void kernel_launch(void* const* d_in, const int* in_sizes, int n_in,
                              void* d_out, int out_size, void* d_ws, size_t ws_size,
                              hipStream_t stream) {
    const float* sdr = (const float*)d_in[0];
    const float* syn = (const float*)d_in[1];
    const int* kptr  = (n_in > 3) ? (const int*)d_in[3] : nullptr;
    float* out = (float*)d_out;
    float* tmp = (float*)d_ws;            // scratch for step-2 pre-sparsify

    // step 1: y = sigmoid(sdr @ W^T) -> d_out (scratch), sparsify in place
    gemv4_sigmoid<<<2048, 256, 0, stream>>>(sdr, syn, out);
    topk_sparsify<<<8, 256, 0, stream>>>(out, out, kptr);
    // step 2: y = sigmoid(act1 @ W^T) -> ws, sparsify -> d_out
    gemv4_sigmoid<<<2048, 256, 0, stream>>>(out, syn, tmp);
    topk_sparsify<<<8, 256, 0, stream>>>(tmp, out, kptr);
}

// Round 5
// 568.252 us; speedup vs baseline: 1.1024x; 1.0068x over previous
//
#include <hip/hip_runtime.h>
#include <cstdint>

// DynamicExpert: act = topk60(sigmoid(act @ synapse.T)), 2 steps.
// B=8, DIM=8192, fp32. Memory-bound on streaming W (268 MB) per step.
// R6 == R4 resubmitted (3rd attempt). Two "container failed twice" errors
//     correlate with a degrading input-push (push_in_npz_s 0 -> 953 -> 1049 s
//     across successful rounds; container attempts likely hit a per-attempt
//     timeout), not with kernel content: full audit finds no OOB, no
//     divergent barriers, legal 64 KB static LDS, no capture violations.
// R4: restructure gemv — stage A in LDS once per block (kills the 512 MB/step
//     A re-read traffic and the per-window A-latency stall that capped R1-R3
//     at ~790-930 GB/s), stream W with no barriers in the hot loop.
//     K split 4 ways (h = former wave-span); partials to ws; the 4-partial
//     combine + sigmoid is fused into the topk kernel in R1's exact order.
//     Per-lane j-order, FMA order, shuffle tree all preserved -> bit-identical.

#define DIM 8192
#define BATCH 8
#define KSPLIT 4
#define KSPAN 2048           // DIM / KSPLIT
#define ROWS_PER_BLK 64
#define GEMV_THREADS 512     // 8 waves
#define ROWS_PER_WAVE 8      // ROWS_PER_BLK / 8 waves

__device__ __forceinline__ float sigmoidf_(float x) {
    return 1.0f / (1.0f + __expf(-x));
}

// Partial gemv: P[h][b][r] = sum_{j in h-span} A[b][j] * W[r][j].
// Block (h, rowgrp): stages A[8][KSPAN] (64 KB LDS) once, then each wave
// computes 8 rows. Per row: 8 coalesced W float4 loads (all issued up
// front, 1 KB/instr), 64 ds_read_b128 A fragments, 256 FMAs, 64-lane
// shuffle tree (R1's exact tree), lane 0 stores the partial.
__global__ __launch_bounds__(GEMV_THREADS) void gemv_part(
    const float* __restrict__ A,
    const float* __restrict__ W,
    float* __restrict__ P)
{
    __shared__ float As[BATCH * KSPAN];   // 64 KB exactly

    const int tid     = threadIdx.x;
    const int h       = blockIdx.x & 3;
    const int rowbase = (blockIdx.x >> 2) * ROWS_PER_BLK;
    const int kbeg    = h * KSPAN;

    // stage A[0..8)[kbeg..kbeg+KSPAN) -> As, float4-coalesced
    {
        const float4* Ag  = (const float4*)A;
        float4*       As4 = (float4*)As;
#pragma unroll
        for (int i = 0; i < 8; ++i) {
            const int q = tid + i * GEMV_THREADS;   // 0..4095
            const int b = q >> 9;                   // 512 float4 per A row span
            const int c = q & 511;
            As4[q] = Ag[b * (DIM / 4) + (kbeg >> 2) + c];
        }
    }
    __syncthreads();

    const int lane = tid & 63;
    const int wid  = tid >> 6;

    for (int t = 0; t < ROWS_PER_WAVE; ++t) {
        const int r = rowbase + wid * ROWS_PER_WAVE + t;
        const float* wr = W + (size_t)r * DIM + kbeg + lane * 4;

        float4 w[8];
#pragma unroll
        for (int win = 0; win < 8; ++win)
            w[win] = *(const float4*)(wr + win * 256);

        float acc[8];
#pragma unroll
        for (int b = 0; b < 8; ++b) acc[b] = 0.0f;

#pragma unroll
        for (int win = 0; win < 8; ++win) {
            const float* abase = As + win * 256 + lane * 4;
#pragma unroll
            for (int b = 0; b < 8; ++b) {
                const float4 a = *(const float4*)(abase + b * KSPAN);
                acc[b] += w[win].x * a.x;
                acc[b] += w[win].y * a.y;
                acc[b] += w[win].z * a.z;
                acc[b] += w[win].w * a.w;
            }
        }

        // 64-lane tree, identical to R1
#pragma unroll
        for (int b = 0; b < 8; ++b) {
            float v = acc[b];
#pragma unroll
            for (int off = 32; off > 0; off >>= 1)
                v += __shfl_down(v, off, 64);
            if (lane == 0)
                P[((size_t)(h * BATCH + b)) * DIM + r] = v;
        }
    }
}

// ---- fused 4-partial reduce + sigmoid + top-k --------------------------
// v = sigmoid(((P0+P1)+P2)+P3)  (same combine order as R1's part[0..3]).
// Then radix top-k (3-level histogram) identical to R2/R3.

__device__ __forceinline__ void scan_small(const int* hist, int nb, int k_need,
                                           int lane, int* s_cut, int* s_gt)
{
    int running = 0;
    for (int cb = nb - 64; cb >= 0; cb -= 64) {
        const int b = cb + 63 - lane;          // lane 0 = highest bucket
        const int val = hist[b];
        int c = val;
#pragma unroll
        for (int o = 1; o < 64; o <<= 1) {
            const int u = __shfl_up(c, o, 64);
            if (lane >= o) c += u;
        }
        const unsigned long long m = __ballot(running + c >= k_need);
        if (m) {
            const int f = (int)__ffsll(m) - 1;
            const int cf = __shfl(c, f, 64);
            const int vf = __shfl(val, f, 64);
            if (lane == 0) { *s_cut = cb + 63 - f; *s_gt = running + cf - vf; }
            return;
        }
        running += __shfl(c, 63, 64);
    }
    if (lane == 0) { *s_cut = 0; *s_gt = 0; }  // unreachable for valid k
}

__device__ __forceinline__ void scan_l1(const int* hist, const int* coarse,
                                        int k_need, int lane,
                                        int* s_cut, int* s_gt)
{
    int running = 0, seg = -1, segGT = 0;
    for (int cb = 192; cb >= 0 && seg < 0; cb -= 64) {
        const int b = cb + 63 - lane;
        const int val = coarse[b];
        int c = val;
#pragma unroll
        for (int o = 1; o < 64; o <<= 1) {
            const int u = __shfl_up(c, o, 64);
            if (lane >= o) c += u;
        }
        const unsigned long long m = __ballot(running + c >= k_need);
        if (m) {
            const int f = (int)__ffsll(m) - 1;
            seg = cb + 63 - f;
            segGT = running + __shfl(c, f, 64) - __shfl(val, f, 64);
        } else {
            running += __shfl(c, 63, 64);
        }
    }
    if (seg < 0) seg = 0;                      // defensive; valid k never hits
    const int b = seg * 32 + 31 - lane;
    const int val = (lane < 32) ? hist[b] : 0;
    int c = val;
#pragma unroll
    for (int o = 1; o < 64; o <<= 1) {
        const int u = __shfl_up(c, o, 64);
        if (lane >= o) c += u;
    }
    const unsigned long long m = __ballot(segGT + c >= k_need);
    const int f = (int)__ffsll(m) - 1;         // crossing is within lanes 0..31
    const int cf = __shfl(c, f, 64);
    const int vf = __shfl(val, f, 64);
    if (lane == 0) { *s_cut = seg * 32 + 31 - f; *s_gt = segGT + cf - vf; }
}

__global__ __launch_bounds__(256) void topk_fused(
    const float* __restrict__ P,        // [KSPLIT][BATCH][DIM] partials
    float* __restrict__ Yout,           // [BATCH][DIM] dense output
    const int* __restrict__ kptr)
{
    const int row  = blockIdx.x;        // batch index b
    const int tid  = threadIdx.x;
    const int lane = tid & 63;
    const int wid  = tid >> 6;
    int k = kptr ? *kptr : 60;
    if (k > DIM) k = DIM;

    // reduce partials (R1's part[0]+part[1]+part[2]+part[3] order) + sigmoid
    uint32_t v[32];
    const float* Pb = P + (size_t)row * DIM;
#pragma unroll
    for (int i = 0; i < 32; ++i) {
        const int idx = tid + i * 256;
        float s = Pb[idx];
        s += Pb[idx + 1 * BATCH * DIM];
        s += Pb[idx + 2 * BATCH * DIM];
        s += Pb[idx + 3 * BATCH * DIM];
        v[i] = __float_as_uint(sigmoidf_(s));
    }

    float* dst = Yout + (size_t)row * DIM;
    if (k <= 0) {
#pragma unroll
        for (int i = 0; i < 32; ++i) dst[tid + i * 256] = 0.0f;
        return;
    }

    __shared__ int hist[8192];     // 32 KB
    __shared__ int coarse[256];
    __shared__ int s_cut, s_gt, s_ctr;

    // ---- level 1: bits >> 17 ----
    for (int i = tid; i < 8192; i += 256) hist[i] = 0;
    __syncthreads();
#pragma unroll
    for (int i = 0; i < 32; ++i) atomicAdd(&hist[v[i] >> 17], 1);
    __syncthreads();
    {
        int s = 0;
        const int base = tid * 32;
        for (int i = 0; i < 32; ++i) s += hist[base + i];
        coarse[tid] = s;
    }
    __syncthreads();
    if (wid == 0) scan_l1(hist, coarse, k, lane, &s_cut, &s_gt);
    __syncthreads();
    const uint32_t cut1 = (uint32_t)s_cut;
    const int gt1 = s_gt;

    // ---- level 2: (bits >> 8) & 0x1FF ----
    for (int i = tid; i < 512; i += 256) hist[i] = 0;
    __syncthreads();
#pragma unroll
    for (int i = 0; i < 32; ++i)
        if ((v[i] >> 17) == cut1) atomicAdd(&hist[(v[i] >> 8) & 0x1FF], 1);
    __syncthreads();
    if (wid == 0) scan_small(hist, 512, k - gt1, lane, &s_cut, &s_gt);
    __syncthreads();
    const uint32_t cut2 = (uint32_t)s_cut;
    const int gt2 = s_gt;

    // ---- level 3: bits & 0xFF ----
    const uint32_t pref = (cut1 << 9) | cut2;
    for (int i = tid; i < 256; i += 256) hist[i] = 0;
    if (tid == 0) s_ctr = 0;
    __syncthreads();
#pragma unroll
    for (int i = 0; i < 32; ++i)
        if ((v[i] >> 8) == pref) atomicAdd(&hist[v[i] & 0xFF], 1);
    __syncthreads();
    if (wid == 0) scan_small(hist, 256, k - gt1 - gt2, lane, &s_cut, &s_gt);
    __syncthreads();
    const uint32_t cut3 = (uint32_t)s_cut;
    const int gt3 = s_gt;

    const uint32_t cutoff  = (pref << 8) | cut3;   // k-th largest value's bits
    const int      need_eq = k - (gt1 + gt2 + gt3);

#pragma unroll
    for (int i = 0; i < 32; ++i) {
        const uint32_t b = v[i];
        float val = 0.0f;
        if (b > cutoff) {
            val = __uint_as_float(b);
        } else if (b == cutoff) {
            const int pos = atomicAdd(&s_ctr, 1);
            if (pos < need_eq) val = __uint_as_float(b);
        }
        dst[tid + i * 256] = val;
    }
}

extern "C" void kernel_launch(void* const* d_in, const int* in_sizes, int n_in,
                              void* d_out, int out_size, void* d_ws, size_t ws_size,
                              hipStream_t stream) {
    const float* sdr = (const float*)d_in[0];
    const float* syn = (const float*)d_in[1];
    const int* kptr  = (n_in > 3) ? (const int*)d_in[3] : nullptr;
    float* out = (float*)d_out;
    float* P   = (float*)d_ws;            // KSPLIT*8*8192 floats = 1 MB

    const int nblk = KSPLIT * (DIM / ROWS_PER_BLK);   // 512

    // step 1: partials = sdr @ W^T (K-split), fused reduce+sigmoid+topk -> out
    gemv_part<<<nblk, GEMV_THREADS, 0, stream>>>(sdr, syn, P);
    topk_fused<<<8, 256, 0, stream>>>(P, out, kptr);
    // step 2: same with act1 as A
    gemv_part<<<nblk, GEMV_THREADS, 0, stream>>>(out, syn, P);
    topk_fused<<<8, 256, 0, stream>>>(P, out, kptr);
}